// Round 4
// baseline (248.789 us; speedup 1.0000x reference)
//
#include <hip/hip_runtime.h>
#include <hip/hip_bf16.h>
#include <stdint.h>

#define LQ 2048
#define LK 2048
#define DH 128
#define BQ 32          // q rows per workgroup (4 waves, grid 512 -> 2 blocks/CU)
#define KB 128         // keys per staged tile
#define NT (LK / KB)   // 16 iterations
#define KROWE 136      // LDS row stride in bf16 elems (272 B = 17 granules; slot 16 is pad)
#define LOG2E 1.44269504088896340736f
#define QSCALE 0.088388347648318447f   // 1/sqrt(128)

typedef __attribute__((ext_vector_type(8)))  short bf16x8;
typedef __attribute__((ext_vector_type(16))) float f32x16;
typedef __attribute__((ext_vector_type(4)))  float f32x4;

typedef __attribute__((address_space(1))) const void glob_cv;
typedef __attribute__((address_space(3))) void lds_v;

union FragAB { uint32_t u[4]; bf16x8 v; };

__device__ __forceinline__ uint32_t pack2_bf16(float lo, float hi) {
  union { __hip_bfloat16 b; uint16_t u; } a, c;
  a.b = __float2bfloat16(lo);
  c.b = __float2bfloat16(hi);
  return (uint32_t)a.u | ((uint32_t)c.u << 16);
}

// ============================================================================
// Pre-pass A: x2 f32 -> K_pre bf16 [b][key][d] and Vt_pre bf16 [b][d][key]
// ============================================================================
__global__ __launch_bounds__(256)
void prep_kernel(const float* __restrict__ x2, uint16_t* __restrict__ Kp,
                 uint16_t* __restrict__ Vp) {
  __shared__ uint16_t tl[128][130];
  const int b = blockIdx.x & 7, tile = blockIdx.x >> 3;
  const int t = threadIdx.x;
  const int row0 = t >> 1, half = t & 1;

  const float* src = x2 + ((size_t)(b * 2048 + tile * 128 + row0)) * 128 + half * 64;
  uint32_t wbuf[32];
#pragma unroll
  for (int i = 0; i < 16; ++i) {
    f32x4 v = *(const f32x4*)(src + i * 4);
    wbuf[2 * i]     = pack2_bf16(v.x, v.y);
    wbuf[2 * i + 1] = pack2_bf16(v.z, v.w);
  }
  uint16_t* kdst = Kp + ((size_t)(b * 2048 + tile * 128 + row0)) * 128 + half * 64;
#pragma unroll
  for (int i = 0; i < 8; ++i)
    *(uint4*)(kdst + i * 8) = *(const uint4*)&wbuf[i * 4];
#pragma unroll
  for (int i = 0; i < 32; ++i)
    *(uint32_t*)&tl[row0][half * 64 + 2 * i] = wbuf[i];
  __syncthreads();

  const int d = t >> 1, halfk = t & 1;
  uint32_t vw[32];
#pragma unroll
  for (int i = 0; i < 32; ++i) {
    const int k = halfk * 64 + 2 * i;
    vw[i] = (uint32_t)tl[k][d] | ((uint32_t)tl[k + 1][d] << 16);
  }
  uint16_t* vdst = Vp + ((size_t)(b * 128 + d)) * 2048 + tile * 128 + halfk * 64;
#pragma unroll
  for (int i = 0; i < 8; ++i)
    *(uint4*)(vdst + i * 8) = *(const uint4*)&vw[i * 4];
}

// ============================================================================
// Pre-pass B: qm * LOG2E -> bf16, packed in per-lane fragment order:
// qmt2[(kc*2+h)][q][gi 0..15] bf16, kc=k>>5, h=(k>>2)&1, gi=(k5>>3)*4+(k&3)
// ============================================================================
__global__ __launch_bounds__(256)
void qmt_kernel(const float* __restrict__ qm, uint16_t* __restrict__ qmt2) {
  const int kc = threadIdx.x & 63;
  const int q  = blockIdx.x * 4 + (threadIdx.x >> 6);
  f32x4 r[8];
  const float* src = qm + (size_t)q * 2048 + kc * 32;
#pragma unroll
  for (int c = 0; c < 8; ++c) r[c] = *(const f32x4*)(src + c * 4);
#pragma unroll
  for (int h = 0; h < 2; ++h) {
    uint32_t w[8];
#pragma unroll
    for (int i = 0; i < 8; ++i) {
      const int gi0 = 2 * i, gi1 = 2 * i + 1;
      const float v0 = r[h + (gi0 >> 2) * 2][gi0 & 3] * LOG2E;
      const float v1 = r[h + (gi1 >> 2) * 2][gi1 & 3] * LOG2E;
      w[i] = pack2_bf16(v0, v1);
    }
    uint16_t* dst = qmt2 + ((size_t)(kc * 2 + h) * 2048 + q) * 16;
    uint4 lo = {w[0], w[1], w[2], w[3]};
    uint4 hi = {w[4], w[5], w[6], w[7]};
    *(uint4*)dst = lo;
    *(uint4*)(dst + 8) = hi;
  }
}

// ============================================================================
// Main flash-attention kernel: 4 waves, 32 q-rows, single-buffered DMA-staged
// K/Vt tiles (68 KB LDS -> 2 blocks/CU), swapped-operand MFMA.
// ============================================================================
__global__ __launch_bounds__(256, 2)
void fattn_kernel(const float* __restrict__ x1,
                  const uint16_t* __restrict__ Kp,
                  const uint16_t* __restrict__ Vp,
                  const float* __restrict__ uu,
                  const uint16_t* __restrict__ qmt2,
                  float* __restrict__ out)
{
  __shared__ char lds[69632];          // K tile [128 keys][272B] + Vt tile [128 d][272B]
  uint16_t* lds16 = (uint16_t*)lds;

  const int tid  = threadIdx.x;
  const int wv   = tid >> 6;           // 0..3 : k-split index
  const int lane = tid & 63;
  const int ln   = lane & 31;
  const int h    = lane >> 5;
  const int ks   = wv;

  const int b     = blockIdx.x & 7;    // batch -> XCD locality
  const int qblk  = blockIdx.x >> 3;   // 0..63
  const int qbase = qblk * BQ;
  const int qrow  = qbase + ln;        // this lane's q row

  // ---- Q fragments (B-operand of S^T mfma), scaled by QSCALE*LOG2E
  FragAB qf[8];
  {
    const float* qp = x1 + ((size_t)(b * LQ + qrow)) * DH + h * 8;
    const float qs = QSCALE * LOG2E;
#pragma unroll
    for (int dc = 0; dc < 8; ++dc) {
      f32x4 a = *(const f32x4*)(qp + dc * 16);
      f32x4 c = *(const f32x4*)(qp + dc * 16 + 4);
      qf[dc].u[0] = pack2_bf16(a.x * qs, a.y * qs);
      qf[dc].u[1] = pack2_bf16(a.z * qs, a.w * qs);
      qf[dc].u[2] = pack2_bf16(c.x * qs, c.y * qs);
      qf[dc].u[3] = pack2_bf16(c.z * qs, c.w * qs);
    }
  }

  // ---- per-lane DMA source offsets: granule G=j*64+lane, row=G/17, slot=G%17
  int koffs[9], voffs[9];
#pragma unroll
  for (int jj = 0; jj < 9; ++jj) {
    const int j = jj * 4 + wv;
    if (j < 34) {
      const int G = j * 64 + lane;
      const int row = (G * 61681) >> 20;        // exact G/17 for G<=2175
      const int s0  = G - row * 17;
      const int s   = (s0 < 16) ? s0 : 0;       // pad slot -> harmless dup
      koffs[jj] = row * 256  + s * 16;          // K_pre [key][256B rows]
      voffs[jj] = row * 4096 + s * 16;          // Vt_pre [d][4096B rows]
    } else { koffs[jj] = 0; voffs[jj] = 0; }
  }
  const char* Kpb = (const char*)(Kp + (size_t)b * 2048 * 128);
  const char* Vpb = (const char*)(Vp + (size_t)b * 128 * 2048);

  // u: lane l covers rows (qbase + 2i + h), key column (ks*32 + ln)
  const float* ub = uu + ((size_t)(b * LQ + qbase + h)) * LK + ks * 32 + ln;

  // ---- stage tile 0 via global_load_lds (wave-uniform LDS dest + lane*16)
#pragma unroll
  for (int jj = 0; jj < 9; ++jj) {
    const int j = jj * 4 + wv;
    if (j < 34) {
      __builtin_amdgcn_global_load_lds((glob_cv*)(Kpb + koffs[jj]),
                                       (lds_v*)(lds + j * 1024), 16, 0, 0);
      __builtin_amdgcn_global_load_lds((glob_cv*)(Vpb + voffs[jj]),
                                       (lds_v*)(lds + 34816 + j * 1024), 16, 0, 0);
    }
  }

  float ucur[16];
#pragma unroll
  for (int i = 0; i < 16; ++i)
    ucur[i] = __builtin_nontemporal_load(ub + (size_t)(2 * i) * LK);

  uint4 qc0, qc1;
  {
    const uint16_t* qp16 = qmt2 + (((size_t)ks * 2 + h) * 2048 + qrow) * 16;
    qc0 = *(const uint4*)qp16;
    qc1 = *(const uint4*)(qp16 + 8);
  }
  __syncthreads();   // drains DMA (compiler emits vmcnt(0) before barrier)

  float m_run = -1e30f, l_run = 0.f;
  f32x16 acco[4];
#pragma unroll
  for (int d2 = 0; d2 < 4; ++d2)
#pragma unroll
    for (int i = 0; i < 16; ++i) acco[d2][i] = 0.f;

  for (int t = 0; t < NT; ++t) {
    // ---- prefetch next u / qm into regs (covers whole compute phase)
    float unxt[16]; uint4 qn0, qn1;
    if (t + 1 < NT) {
#pragma unroll
      for (int i = 0; i < 16; ++i)
        unxt[i] = __builtin_nontemporal_load(ub + (size_t)((t + 1) * KB) + (size_t)(2 * i) * LK);
      const uint16_t* qp16 = qmt2 + (((size_t)((t + 1) * 4 + ks) * 2 + h) * 2048 + qrow) * 16;
      qn0 = *(const uint4*)qp16;
      qn1 = *(const uint4*)(qp16 + 8);
    }

    // ---- QK: S^T(32k x 32q) = K(32k x 16d) * Q^T(16d x 32q)
    f32x16 sacc;
#pragma unroll
    for (int i = 0; i < 16; ++i) sacc[i] = 0.f;
    const uint16_t* Krow = lds16 + (size_t)(ks * 32 + ln) * KROWE + h * 8;
    __builtin_amdgcn_s_setprio(1);
#pragma unroll
    for (int dc = 0; dc < 8; ++dc) {
      bf16x8 af = *(const bf16x8*)(Krow + dc * 16);
      sacc = __builtin_amdgcn_mfma_f32_32x32x16_bf16(af, qf[dc].v, sacc, 0, 0, 0);
    }
    __builtin_amdgcn_s_setprio(0);

    // ---- add qm*LOG2E (bf16 pre-packed in fragment order)
#define ADDQM(W, I) { sacc[I] += __uint_as_float((W) << 16); \
                      sacc[I + 1] += __uint_as_float((W) & 0xffff0000u); }
    ADDQM(qc0.x, 0)  ADDQM(qc0.y, 2)  ADDQM(qc0.z, 4)  ADDQM(qc0.w, 6)
    ADDQM(qc1.x, 8)  ADDQM(qc1.y, 10) ADDQM(qc1.z, 12) ADDQM(qc1.w, 14)
#undef ADDQM

    // ---- online softmax (log2 domain; lane owns q-row)
    float pm = sacc[0];
#pragma unroll
    for (int i = 1; i < 16; ++i) pm = fmaxf(pm, sacc[i]);
    pm = fmaxf(pm, __shfl_xor(pm, 32));
    const float mnew = fmaxf(m_run, pm);
    const float resc = __builtin_amdgcn_exp2f(m_run - mnew);
    m_run = mnew;
    float rs = 0.f;
#pragma unroll
    for (int i = 0; i < 16; ++i) {
      sacc[i] = __builtin_amdgcn_exp2f(sacc[i] - mnew);
      rs += sacc[i];
    }
    rs += __shfl_xor(rs, 32);
    l_run = l_run * resc + rs;          // denominator WITHOUT dropout

    // ---- dropout keep-bits via ballot (coalesced u already in regs)
    uint32_t M = 0;
#pragma unroll
    for (int i = 0; i < 16; ++i) {
      unsigned long long bi = __ballot(ucur[i] >= 0.1f);
      uint32_t sel = (ln & 1) ? (uint32_t)(bi >> 32) : (uint32_t)bi;
      M = ((ln >> 1) == i) ? sel : M;
    }
#pragma unroll
    for (int g = 0; g < 4; ++g)
#pragma unroll
      for (int j2 = 0; j2 < 4; ++j2) {
        const uint32_t keep = (M >> (h * 4 + g * 8 + j2)) & 1u;
        sacc[g * 4 + j2] = keep ? sacc[g * 4 + j2] : 0.f;
      }

    // ---- pack bf16 pairs + exchange key-halves across lane-32 boundary
    uint32_t pr[4][2], sw[4][2];
#pragma unroll
    for (int g = 0; g < 4; ++g) {
      pr[g][0] = pack2_bf16(sacc[4 * g + 0], sacc[4 * g + 1]);
      pr[g][1] = pack2_bf16(sacc[4 * g + 2], sacc[4 * g + 3]);
      sw[g][0] = __shfl_xor(pr[g][0], 32);
      sw[g][1] = __shfl_xor(pr[g][1], 32);
    }
    FragAB bfr[2];
#pragma unroll
    for (int c = 0; c < 2; ++c) {
      bfr[c].u[0] = h ? sw[2 * c + 1][0] : pr[2 * c][0];
      bfr[c].u[1] = h ? sw[2 * c + 1][1] : pr[2 * c][1];
      bfr[c].u[2] = h ? pr[2 * c + 1][0] : sw[2 * c][0];
      bfr[c].u[3] = h ? pr[2 * c + 1][1] : sw[2 * c][1];
    }

    // ---- rescale running accumulator
#pragma unroll
    for (int d2 = 0; d2 < 4; ++d2)
#pragma unroll
      for (int i = 0; i < 16; ++i) acco[d2][i] *= resc;

    // ---- PV: out^T(32d x 32q) += V^T(32d x 16k) * P(16k x 32q)
    __builtin_amdgcn_s_setprio(1);
#pragma unroll
    for (int d2 = 0; d2 < 4; ++d2) {
      const uint16_t* Vrow = lds16 + 17408 + (size_t)(d2 * 32 + ln) * KROWE + ks * 32 + h * 8;
#pragma unroll
      for (int c = 0; c < 2; ++c) {
        bf16x8 av = *(const bf16x8*)(Vrow + c * 16);
        acco[d2] = __builtin_amdgcn_mfma_f32_32x32x16_bf16(av, bfr[c].v, acco[d2], 0, 0, 0);
      }
    }
    __builtin_amdgcn_s_setprio(0);

    __syncthreads();                    // A: all waves done reading tile t
    if (t + 1 < NT) {
      const char* kp = Kpb + (size_t)(t + 1) * 32768;
      const char* vp = Vpb + (size_t)(t + 1) * 256;
#pragma unroll
      for (int jj = 0; jj < 9; ++jj) {
        const int j = jj * 4 + wv;
        if (j < 34) {
          __builtin_amdgcn_global_load_lds((glob_cv*)(kp + koffs[jj]),
                                           (lds_v*)(lds + j * 1024), 16, 0, 0);
          __builtin_amdgcn_global_load_lds((glob_cv*)(vp + voffs[jj]),
                                           (lds_v*)(lds + 34816 + j * 1024), 16, 0, 0);
        }
      }
#pragma unroll
      for (int i = 0; i < 16; ++i) ucur[i] = unxt[i];
      qc0 = qn0; qc1 = qn1;
      __syncthreads();                  // B: DMA drained (vmcnt(0) at barrier)
    }
  }

  // ---- k-split merge through LDS (scratch overlays staging buffers)
  float* scr = (float*)lds + (size_t)wv * 4224;
  scr[lane]      = m_run;
  scr[64 + lane] = l_run;
#pragma unroll
  for (int d2 = 0; d2 < 4; ++d2)
#pragma unroll
    for (int g = 0; g < 4; ++g) {
      f32x4 vv;
#pragma unroll
      for (int j2 = 0; j2 < 4; ++j2) vv[j2] = acco[d2][g * 4 + j2];
      *(f32x4*)(scr + 128 + (size_t)(d2 * 4 + g) * 256 + lane * 4) = vv;
    }
  __syncthreads();

  if (wv < 2) {
    const float* rg[4];
#pragma unroll
    for (int s2 = 0; s2 < 4; ++s2) rg[s2] = (const float*)lds + (size_t)s2 * 4224;
    const float ms0 = rg[0][lane], ms1 = rg[1][lane], ms2 = rg[2][lane], ms3 = rg[3][lane];
    const float ls0 = rg[0][64 + lane], ls1 = rg[1][64 + lane];
    const float ls2 = rg[2][64 + lane], ls3 = rg[3][64 + lane];
    const float mM = fmaxf(fmaxf(ms0, ms1), fmaxf(ms2, ms3));
    const float e0 = __builtin_amdgcn_exp2f(ms0 - mM);
    const float e1 = __builtin_amdgcn_exp2f(ms1 - mM);
    const float e2 = __builtin_amdgcn_exp2f(ms2 - mM);
    const float e3 = __builtin_amdgcn_exp2f(ms3 - mM);
    const float lM = e0 * ls0 + e1 * ls1 + e2 * ls2 + e3 * ls3;
    const float inv = (1.0f / 0.9f) / lM;   // fold dropout 1/(1-p) into normalization
    float* op = out + ((size_t)(b * LQ + qbase + ln)) * DH;
#pragma unroll
    for (int dd = 0; dd < 2; ++dd) {
      const int d2 = wv * 2 + dd;
#pragma unroll
      for (int g = 0; g < 4; ++g) {
        const size_t off = 128 + (size_t)(d2 * 4 + g) * 256 + lane * 4;
        f32x4 a4 = e0 * *(const f32x4*)(rg[0] + off)
                 + e1 * *(const f32x4*)(rg[1] + off)
                 + e2 * *(const f32x4*)(rg[2] + off)
                 + e3 * *(const f32x4*)(rg[3] + off);
        a4 = a4 * inv;
        *(f32x4*)(op + d2 * 32 + 8 * g + 4 * h) = a4;
      }
    }
  }
}

extern "C" void kernel_launch(void* const* d_in, const int* in_sizes, int n_in,
                              void* d_out, int out_size, void* d_ws, size_t ws_size,
                              hipStream_t stream) {
  (void)in_sizes; (void)n_in; (void)out_size; (void)ws_size;
  const float* x1 = (const float*)d_in[0];
  const float* x2 = (const float*)d_in[1];
  const float* qm = (const float*)d_in[2];
  const float* u  = (const float*)d_in[3];
  float* out = (float*)d_out;

  uint16_t* qmt2 = (uint16_t*)d_ws;                            // 8 MB
  uint16_t* Kp   = (uint16_t*)((char*)d_ws + (8u  << 20));     // 4 MB
  uint16_t* Vp   = (uint16_t*)((char*)d_ws + (12u << 20));     // 4 MB

  prep_kernel<<<dim3(128), dim3(256), 0, stream>>>(x2, Kp, Vp);
  qmt_kernel<<<dim3(512), dim3(256), 0, stream>>>(qm, qmt2);
  fattn_kernel<<<dim3(512), dim3(256), 0, stream>>>(x1, Kp, Vp, u, qmt2, out);
}